// Round 2
// baseline (173.632 us; speedup 1.0000x reference)
//
#include <hip/hip_runtime.h>
#include <hip/hip_bf16.h>
#include <math.h>

#define NHEADS 4
#define NM 32
#define CIN 32
#define COUT 32
#define BATCH 2
#define NPTS (48*48*48)           // 110592 per batch
#define PAD 36                    // padded LDS row (bf16) for k_out tiles
#define PTS_AX 288                // points per k_ax block (9 chunks of 32)
#define SEGS_AX (NPTS/PTS_AX)     // 384 -> grid 768 = exactly 3 blocks/CU
#define PADT 292                  // s_aT row stride (ushort): 584B, bank step 18 -> 2-way (free)
#define SEGS_OUT (NPTS/128)       // 864
#define NRED 512                  // reduction blocks (16384 floats / 32 per block)
#define INV_N (1.0f / (float)NPTS)

typedef unsigned short ushort_t;
typedef __attribute__((ext_vector_type(8))) short short8;     // 8 x bf16 frag
typedef __attribute__((ext_vector_type(16))) float floatx16;  // 32x32 C/D frag

#define MFMA32 __builtin_amdgcn_mfma_f32_32x32x16_bf16

union frag8 { short8 v; uint2 u2[2]; unsigned u[4]; ushort_t s[8]; };

__device__ __forceinline__ floatx16 zero16() {
    floatx16 z;
#pragma unroll
    for (int i = 0; i < 16; ++i) z[i] = 0.0f;
    return z;
}
__device__ __forceinline__ ushort_t f2bf(float f) {
    __hip_bfloat16 h = __float2bfloat16(f);
    return *(ushort_t*)&h;
}
__device__ __forceinline__ float bf2f(ushort_t u) {
    union { unsigned i; float f; } v; v.i = ((unsigned)u) << 16; return v.f;
}
__device__ __forceinline__ unsigned pk2(float a, float b) {
    return (unsigned)f2bf(a) | ((unsigned)f2bf(b) << 16);
}
__device__ __forceinline__ short8 frag_lds(const ushort_t* p) {
    frag8 r;
    r.u2[0] = *(const uint2*)p;
    r.u2[1] = *(const uint2*)(p + 4);
    return r.v;
}

// ---------------------------------------------------------------------------
// k_ax: M[b,h,i,g] = sum_n a[n,i]*X[n,g]. a staged TRANSPOSED in LDS once;
// X built directly into B-op fragments. Wave = head. One __syncthreads.
// Output: per-block partials. Also zeroes the k_redw completion counter.
// ---------------------------------------------------------------------------
__global__ __launch_bounds__(256, 4) void k_ax(
    const float* __restrict__ a, const float* __restrict__ x,
    const float* __restrict__ x_modes,
    float* __restrict__ AX, float* __restrict__ part,
    unsigned* __restrict__ cnt, int use_part)
{
    __shared__ ushort_t s_aT[CIN][PADT];   // a^T bf16 [i][pt]
    __shared__ float4   s_x4[PTS_AX];      // x as vec4 per point

    const int t = threadIdx.x;
    const int w = t >> 6;              // wave id == head
    const int l = t & 63;
    const int l31 = l & 31, lh = l >> 5;
    const int b  = blockIdx.x / SEGS_AX;
    const int sb = blockIdx.x % SEGS_AX;
    const int pbase = b * NPTS + sb * PTS_AX;

    if (blockIdx.x == 0 && t == 0)
        __hip_atomic_store(cnt, 0u, __ATOMIC_RELAXED, __HIP_MEMORY_SCOPE_AGENT);

    // stage a transposed (bf16) and x (vec4)
    for (int pt = t; pt < PTS_AX; pt += 256) {
        const float* arow = a + (size_t)(pbase + pt) * CIN;
#pragma unroll
        for (int v = 0; v < 8; ++v) {
            float4 f = ((const float4*)arow)[v];
            s_aT[4*v+0][pt] = f2bf(f.x);
            s_aT[4*v+1][pt] = f2bf(f.y);
            s_aT[4*v+2][pt] = f2bf(f.z);
            s_aT[4*v+3][pt] = f2bf(f.w);
        }
    }
    for (int idx = t; idx < PTS_AX*3; idx += 256) {
        const float v = x[(size_t)pbase * 3 + idx];
        const int pt = idx / 3;
        ((float*)&s_x4[pt])[idx - 3*pt] = v;
    }
    // x_modes row for lane's g = l31
    const float xm0 = x_modes[(w*NM + l31)*3 + 0];
    const float xm1 = x_modes[(w*NM + l31)*3 + 1];
    const float xm2 = x_modes[(w*NM + l31)*3 + 2];

    floatx16 accre = zero16(), accim = zero16();
    __syncthreads();   // only block barrier

    for (int c = 0; c < PTS_AX/32; ++c) {
        const int p0 = c * 32;
        // ---- X frags direct: B-op [n=g=l31][k=pt], pt = p0+kh*16+lh*8+j ----
        short8 xre[2], xim[2];
#pragma unroll
        for (int kh = 0; kh < 2; ++kh) {
            frag8 re_, im_;
#pragma unroll
            for (int j = 0; j < 8; j += 2) {
                const int pl = p0 + kh*16 + lh*8 + j;
                const float4 v0 = s_x4[pl], v1 = s_x4[pl + 1];
                const float q0 = v0.x*xm0 + v0.y*xm1 + v0.z*xm2;
                const float q1 = v1.x*xm0 + v1.y*xm1 + v1.z*xm2;
                re_.u[j>>1] = pk2( __builtin_amdgcn_cosf(q0),  __builtin_amdgcn_cosf(q1));
                im_.u[j>>1] = pk2(-__builtin_amdgcn_sinf(q0), -__builtin_amdgcn_sinf(q1));
            }
            xre[kh] = re_.v; xim[kh] = im_.v;
        }
        // ---- M accumulate: A-op a^T [m=i=l31][k=pt] straight from LDS ----
#pragma unroll
        for (int kh = 0; kh < 2; ++kh) {
            short8 atf = frag_lds(&s_aT[l31][p0 + kh*16 + lh*8]);
            accre = MFMA32(atf, xre[kh], accre, 0, 0, 0);
            accim = MFMA32(atf, xim[kh], accim, 0, 0, 0);
        }
    }

    // M[i,g]: i = row(r), g = l31 (32x32x16 C/D layout)
    if (use_part) {
        float* pr = part + (size_t)blockIdx.x * 8192;
#pragma unroll
        for (int r = 0; r < 16; ++r) {
            const int ir = (r & 3) + 8*(r >> 2) + 4*lh;
            const int idx = (w*NM + ir)*NM + l31;
            pr[idx]        = accre[r];
            pr[idx + 4096] = accim[r];
        }
    } else {
        float* Mre = AX;
        float* Mim = AX + BATCH*NHEADS*NM*NM;
#pragma unroll
        for (int r = 0; r < 16; ++r) {
            const int ir = (r & 3) + 8*(r >> 2) + 4*lh;
            const int idx = b*4096 + (w*NM + ir)*NM + l31;
            atomicAdd(&Mre[idx], accre[r]);
            atomicAdd(&Mim[idx], accim[r]);
        }
    }
}

// ---------------------------------------------------------------------------
// k_redw: phase 1 (512 blocks) -- M = sum of 384 partials, float4-vectorized:
// each block owns one 32-float M row (1 KB/wave-instr loads). Last finished
// block (atomic counter, agent acq_rel) computes P = um^T.am per head, then
// W = (P.M)*INV_N in bf16 -- replaces the separate k_w dispatch.
// ---------------------------------------------------------------------------
__global__ void k_redw(const float* __restrict__ part,
                       const float* __restrict__ a_modes,
                       const float* __restrict__ u_modes,
                       float* __restrict__ AX, ushort_t* __restrict__ W,
                       unsigned* __restrict__ cnt)
{
    __shared__ float4   s_r[32][8];
    __shared__ float    sAm[4][32][32];
    __shared__ float    sUm[4][32][32];
    __shared__ float    sP[4][32][33];
    __shared__ unsigned s_last;

    const int t = threadIdx.x;
    const int blk = blockIdx.x;
    const int bb = blk >> 8;                 // batch
    const int idx0 = (blk & 255) * 32;       // flat idx within [0,8192)
    const int c = t & 7, s = t >> 3;

    // ---- phase 1: reduce 384 partials for this block's 32 floats ----
    {
        const float4* p4 = (const float4*)part;
        const size_t colbase = (size_t)bb * SEGS_AX * 2048 + (idx0 >> 2) + c;
        float4 acc = {0.f, 0.f, 0.f, 0.f};
#pragma unroll 4
        for (int k = 0; k < 12; ++k) {
            const float4 v = p4[colbase + (size_t)(s + 32*k) * 2048];
            acc.x += v.x; acc.y += v.y; acc.z += v.z; acc.w += v.w;
        }
        s_r[s][c] = acc;
    }
    __syncthreads();
    if (t < 8) {
        float4 v = s_r[0][t];
#pragma unroll
        for (int ss = 1; ss < 32; ++ss) {
            const float4 u = s_r[ss][t];
            v.x += u.x; v.y += u.y; v.z += u.z; v.w += u.w;
        }
        float* dst = (idx0 < 4096) ? (AX + bb*4096 + idx0)
                                   : (AX + 8192 + bb*4096 + (idx0 - 4096));
        ((float4*)dst)[t] = v;
    }
    __syncthreads();   // M stores drained (barrier waits vmcnt) before release
    if (t == 0) {
        __threadfence();
        const unsigned prev = __hip_atomic_fetch_add(
            cnt, 1u, __ATOMIC_ACQ_REL, __HIP_MEMORY_SCOPE_AGENT);
        s_last = (prev == (unsigned)(NRED - 1)) ? 1u : 0u;
    }
    __syncthreads();
    if (!s_last) return;
    __threadfence();   // acquire for all threads of the last block

    // ---- last block: stage am/um, build P[h] = um^T.am ----
    {
        const float4* am4 = (const float4*)a_modes;
        const float4* um4 = (const float4*)u_modes;
        float4* sa4 = (float4*)&sAm[0][0][0];
        float4* su4 = (float4*)&sUm[0][0][0];
        for (int e = t; e < 1024; e += 256) { sa4[e] = am4[e]; su4[e] = um4[e]; }
    }
    __syncthreads();
#pragma unroll
    for (int k = 0; k < 16; ++k) {
        const int e = k*256 + t;
        const int h = e >> 10, o = (e >> 5) & 31, i = e & 31;
        float p = 0.f;
#pragma unroll
        for (int f = 0; f < 32; ++f)
            p += sUm[h][f][o] * sAm[h][f][i];
        sP[h][o][i] = p;
    }
    __syncthreads();

    // ---- W[b,h,o,g] = INV_N * sum_i P[h,o,i] * M[b,h,i,g], bf16 out ----
    {
        const int grp = t >> 3;                    // [0,32)
        const int g0 = (t & 7) * 4;
        const int b = grp >> 4, h = (grp >> 2) & 3, oq = grp & 3;
        const float* Mre = AX + b*4096 + h*1024;
        const float* Mim = AX + 8192 + b*4096 + h*1024;
        float4 ar[8], ai[8];
#pragma unroll
        for (int o8 = 0; o8 < 8; ++o8) {
            ar[o8] = {0.f,0.f,0.f,0.f}; ai[o8] = {0.f,0.f,0.f,0.f};
        }
#pragma unroll 4
        for (int i = 0; i < 32; ++i) {
            const float4 mr = *(const float4*)&Mre[i*32 + g0];
            const float4 mi = *(const float4*)&Mim[i*32 + g0];
#pragma unroll
            for (int o8 = 0; o8 < 8; ++o8) {
                const float p = sP[h][oq*8 + o8][i];
                ar[o8].x += p*mr.x; ar[o8].y += p*mr.y;
                ar[o8].z += p*mr.z; ar[o8].w += p*mr.w;
                ai[o8].x += p*mi.x; ai[o8].y += p*mi.y;
                ai[o8].z += p*mi.z; ai[o8].w += p*mi.w;
            }
        }
        ushort_t* Wre = W + (size_t)(b*4 + h) * 1024;
        ushort_t* Wim = Wre + 8192;
#pragma unroll
        for (int o8 = 0; o8 < 8; ++o8) {
            const int o = oq*8 + o8;
            uint2 pr, pi;
            pr.x = pk2(ar[o8].x*INV_N, ar[o8].y*INV_N);
            pr.y = pk2(ar[o8].z*INV_N, ar[o8].w*INV_N);
            pi.x = pk2(ai[o8].x*INV_N, ai[o8].y*INV_N);
            pi.y = pk2(ai[o8].z*INV_N, ai[o8].w*INV_N);
            *(uint2*)&Wre[o*32 + g0] = pr;
            *(uint2*)&Wim[o*32 + g0] = pi;
        }
    }
}

// ---------------------------------------------------------------------------
// k_w_fb: fallback (tiny-workspace path only): W = um.(am.M)*INV_N.
// ---------------------------------------------------------------------------
__global__ void k_w_fb(const float* __restrict__ AX, const float* __restrict__ a_modes,
                       const float* __restrict__ u_modes, ushort_t* __restrict__ W)
{
    __shared__ float sM[2][NM][NM];
    __shared__ float sT[2][NM][NM + 1];
    const int t = threadIdx.x;
    const int b = blockIdx.x >> 2, h = blockIdx.x & 3;
    const float* Mre = AX + b*4096 + h*1024;
    const float* Mim = AX + BATCH*4096 + b*4096 + h*1024;
    for (int i = t; i < 1024; i += 256) {
        sM[0][i >> 5][i & 31] = Mre[i];
        sM[1][i >> 5][i & 31] = Mim[i];
    }
    __syncthreads();
    const int fo = t >> 3;
    const int g0 = (t & 7) * 4;
    {
        const float* am = a_modes + (h*NM + fo)*CIN;
        float tr[4] = {0,0,0,0}, ti[4] = {0,0,0,0};
#pragma unroll 8
        for (int i = 0; i < CIN; ++i) {
            const float wv = am[i];
#pragma unroll
            for (int j = 0; j < 4; ++j) {
                tr[j] += wv * sM[0][i][g0+j];
                ti[j] += wv * sM[1][i][g0+j];
            }
        }
#pragma unroll
        for (int j = 0; j < 4; ++j) { sT[0][fo][g0+j] = tr[j]; sT[1][fo][g0+j] = ti[j]; }
    }
    __syncthreads();
    {
        float wr[4] = {0,0,0,0}, wi[4] = {0,0,0,0};
#pragma unroll 8
        for (int f = 0; f < NM; ++f) {
            const float wv = u_modes[(h*NM + f)*COUT + fo];
#pragma unroll
            for (int j = 0; j < 4; ++j) {
                wr[j] += wv * sT[0][f][g0+j];
                wi[j] += wv * sT[1][f][g0+j];
            }
        }
        ushort_t* Wre = W + (size_t)blockIdx.x * 1024;
        ushort_t* Wim = Wre + 8192;
#pragma unroll
        for (int j = 0; j < 4; ++j) {
            Wre[fo*NM + g0 + j] = f2bf(wr[j] * INV_N);
            Wim[fo*NM + g0 + j] = f2bf(wi[j] * INV_N);
        }
    }
}

// ---------------------------------------------------------------------------
// k_out: out = gelu( Re(Y*W) + a.fc_w^T + fc_b ); Y frags built directly.
// Wave = 32 points; one __syncthreads total. (Unchanged.)
// ---------------------------------------------------------------------------
__global__ __launch_bounds__(256, 4) void k_out(
    const float* __restrict__ a, const float* __restrict__ y,
    const float* __restrict__ y_modes, const ushort_t* __restrict__ Wg,
    const float* __restrict__ fc_w, const float* __restrict__ fc_b,
    float* __restrict__ out)
{
    __shared__ ushort_t s_Wre[NHEADS][NM][PAD];  // [h][o][g]
    __shared__ ushort_t s_Wim[NHEADS][NM][PAD];
    __shared__ float4   s_ym4[NHEADS][NM];       // y_modes vec4 per (h,g)
    __shared__ float4   s_y4[128];               // y vec4 per point
    __shared__ ushort_t s_ah[128][PAD];          // a tile bf16 [pt][i]

    const int t = threadIdx.x, w = t >> 6, l = t & 63;
    const int l31 = l & 31, lh = l >> 5;
    const int b  = blockIdx.x / SEGS_OUT;
    const int sb = blockIdx.x % SEGS_OUT;
    const int pblock = b * NPTS + sb * 128;
    const int pwave  = pblock + w * 32;

    // ---- stage ----
    {
        const unsigned* wr = (const unsigned*)Wg + b*2048;
        const unsigned* wi = (const unsigned*)(Wg + 8192) + b*2048;
        for (int idx2 = t; idx2 < 2048; idx2 += 256) {
            const int h = idx2 >> 9, o = (idx2 >> 4) & 31, g2 = (idx2 & 15) * 2;
            *(unsigned*)&s_Wre[h][o][g2] = wr[idx2];
            *(unsigned*)&s_Wim[h][o][g2] = wi[idx2];
        }
    }
    if (t < 128) {
        const int h = t >> 5, g = t & 31;
        const float* p = y_modes + (h*NM + g)*3;
        float4 v; v.x = p[0]; v.y = p[1]; v.z = p[2]; v.w = 0.f;
        s_ym4[h][g] = v;
    }
    for (int idx = t; idx < 128*3; idx += 256) {
        const float v = y[(size_t)pblock * 3 + idx];
        const int pt = idx / 3;
        ((float*)&s_y4[pt])[idx - 3*pt] = v;
    }
    if (t < 128) {
        const float* arow = a + (size_t)(pblock + t) * CIN;
        unsigned* dst = (unsigned*)&s_ah[t][0];
#pragma unroll
        for (int v = 0; v < 8; ++v) {
            float4 f = ((const float4*)arow)[v];
            dst[2*v]   = pk2(f.x, f.y);
            dst[2*v+1] = pk2(f.z, f.w);
        }
    }
    // fc_w hi/lo split frags: B-op [n=o=l31][k=i]
    short8 whi[2], wlo[2];
#pragma unroll
    for (int kh = 0; kh < 2; ++kh) {
        const float* p = fc_w + l31*CIN + kh*16 + lh*8;
        float4 f0 = ((const float4*)p)[0], f1 = ((const float4*)p)[1];
        float v[8] = {f0.x,f0.y,f0.z,f0.w,f1.x,f1.y,f1.z,f1.w};
        frag8 hi, lo;
#pragma unroll
        for (int j = 0; j < 8; ++j) {
            const ushort_t hb = f2bf(v[j]);
            hi.s[j] = hb;
            lo.s[j] = f2bf(v[j] - bf2f(hb));
        }
        whi[kh] = hi.v; wlo[kh] = lo.v;
    }
    const float fb = fc_b[l31];

    __syncthreads();   // only block barrier
    const float4 y3 = s_y4[w*32 + l31];

    // ---- skip: D[pt][o] = sum_i a[pt][i]*(whi+wlo)[o][i] ----
    floatx16 acc = zero16();
#pragma unroll
    for (int kh = 0; kh < 2; ++kh) {
        short8 af = frag_lds(&s_ah[w*32 + l31][kh*16 + lh*8]);  // A-op [m=pt][k=i]
        acc = MFMA32(af, whi[kh], acc, 0, 0, 0);
        acc = MFMA32(af, wlo[kh], acc, 0, 0, 0);
    }
    // ---- heads: acc += Yre.Wre + (-Yim).Wim ----
    for (int h = 0; h < NHEADS; ++h) {
        short8 yre[2], yim[2];
#pragma unroll
        for (int kh = 0; kh < 2; ++kh) {
            frag8 re_, im_;
#pragma unroll
            for (int j = 0; j < 8; j += 2) {
                const int g0 = kh*16 + lh*8 + j;
                const float4 m0 = s_ym4[h][g0], m1 = s_ym4[h][g0 + 1];
                const float p0 = y3.x*m0.x + y3.y*m0.y + y3.z*m0.z;
                const float p1 = y3.x*m1.x + y3.y*m1.y + y3.z*m1.z;
                re_.u[j>>1] = pk2( __builtin_amdgcn_cosf(p0),  __builtin_amdgcn_cosf(p1));
                im_.u[j>>1] = pk2(-__builtin_amdgcn_sinf(p0), -__builtin_amdgcn_sinf(p1));
            }
            yre[kh] = re_.v; yim[kh] = im_.v;
        }
#pragma unroll
        for (int kh = 0; kh < 2; ++kh) {
            short8 wrf = frag_lds(&s_Wre[h][l31][kh*16 + lh*8]);  // B-op [n=o][k=g]
            short8 wif = frag_lds(&s_Wim[h][l31][kh*16 + lh*8]);
            acc = MFMA32(yre[kh], wrf, acc, 0, 0, 0);
            acc = MFMA32(yim[kh], wif, acc, 0, 0, 0);
        }
    }
    // ---- epilogue: bias + exact GELU + store ----
#pragma unroll
    for (int r = 0; r < 16; ++r) {
        const int ptr_ = (r & 3) + 8*(r >> 2) + 4*lh;
        const float z = acc[r] + fb;
        out[(size_t)(pwave + ptr_) * COUT + l31] =
            0.5f * z * (1.0f + erff(z * 0.70710678118654752f));
    }
}

extern "C" void kernel_launch(void* const* d_in, const int* in_sizes, int n_in,
                              void* d_out, int out_size, void* d_ws, size_t ws_size,
                              hipStream_t stream) {
    (void)in_sizes; (void)n_in; (void)out_size;
    const float* a       = (const float*)d_in[0];
    const float* x       = (const float*)d_in[1];
    const float* y       = (const float*)d_in[2];
    const float* a_modes = (const float*)d_in[3];
    const float* x_modes = (const float*)d_in[4];
    const float* y_modes = (const float*)d_in[5];
    const float* u_modes = (const float*)d_in[6];
    const float* fc_w    = (const float*)d_in[7];
    const float* fc_b    = (const float*)d_in[8];
    float* out  = (float*)d_out;
    float*    AX   = (float*)d_ws;                          // 16384 f32 = 64 KB (holds M)
    ushort_t* W    = (ushort_t*)((char*)d_ws + 65536);      // 16384 bf16 = 32 KB
    unsigned* cnt  = (unsigned*)((char*)d_ws + 98304);      // completion counter
    float*    part = (float*)((char*)d_ws + 99328);         // 768*8192 f32 = 25.2 MB

    const size_t need = 99328 + (size_t)BATCH * SEGS_AX * 8192 * sizeof(float);
    const int use_part = (ws_size >= need) ? 1 : 0;

    if (!use_part) hipMemsetAsync(AX, 0, 65536, stream);  // atomic fallback needs zeroed M
    k_ax<<<BATCH * SEGS_AX, 256, 0, stream>>>(a, x, x_modes, AX, part, cnt, use_part);
    if (use_part) k_redw<<<NRED, 256, 0, stream>>>(part, a_modes, u_modes, AX, W, cnt);
    else          k_w_fb<<<8, 256, 0, stream>>>(AX, a_modes, u_modes, W);
    k_out<<<BATCH * SEGS_OUT, 256, 0, stream>>>(a, y, y_modes, W, fc_w, fc_b, out);
}

// Round 3
// 148.342 us; speedup vs baseline: 1.1705x; 1.1705x over previous
//
#include <hip/hip_runtime.h>
#include <hip/hip_bf16.h>
#include <math.h>

#define NHEADS 4
#define NM 32
#define CIN 32
#define COUT 32
#define BATCH 2
#define NPTS (48*48*48)           // 110592 per batch
#define PAD 36                    // padded LDS row (bf16) for k_out tiles
#define PTS_AX 288                // points per k_ax block (9 chunks of 32)
#define SEGS_AX (NPTS/PTS_AX)     // 384 -> grid 768 = exactly 3 blocks/CU
#define PADT 292                  // s_aT row stride (ushort): 584B, bank step 18 -> 2-way (free)
#define SEGS_OUT (NPTS/128)       // 864
#define NRED 512                  // reduction blocks (16384 floats / 32 per block)
#define INV_N (1.0f / (float)NPTS)

typedef unsigned short ushort_t;
typedef __attribute__((ext_vector_type(8))) short short8;     // 8 x bf16 frag
typedef __attribute__((ext_vector_type(16))) float floatx16;  // 32x32 C/D frag

#define MFMA32 __builtin_amdgcn_mfma_f32_32x32x16_bf16

union frag8 { short8 v; uint2 u2[2]; unsigned u[4]; ushort_t s[8]; };

__device__ __forceinline__ floatx16 zero16() {
    floatx16 z;
#pragma unroll
    for (int i = 0; i < 16; ++i) z[i] = 0.0f;
    return z;
}
__device__ __forceinline__ ushort_t f2bf(float f) {
    __hip_bfloat16 h = __float2bfloat16(f);
    return *(ushort_t*)&h;
}
__device__ __forceinline__ float bf2f(ushort_t u) {
    union { unsigned i; float f; } v; v.i = ((unsigned)u) << 16; return v.f;
}
__device__ __forceinline__ unsigned pk2(float a, float b) {
    return (unsigned)f2bf(a) | ((unsigned)f2bf(b) << 16);
}
__device__ __forceinline__ short8 frag_lds(const ushort_t* p) {
    frag8 r;
    r.u2[0] = *(const uint2*)p;
    r.u2[1] = *(const uint2*)(p + 4);
    return r.v;
}

// ---------------------------------------------------------------------------
// k_ax: M[b,h,i,g] = sum_n a[n,i]*X[n,g]. a staged TRANSPOSED in LDS once;
// X built directly into B-op fragments. Wave = head. One __syncthreads.
// Output: per-block partials. (Round-1 version; no sync counter.)
// ---------------------------------------------------------------------------
__global__ __launch_bounds__(256, 4) void k_ax(
    const float* __restrict__ a, const float* __restrict__ x,
    const float* __restrict__ x_modes,
    float* __restrict__ AX, float* __restrict__ part, int use_part)
{
    __shared__ ushort_t s_aT[CIN][PADT];   // a^T bf16 [i][pt]
    __shared__ float4   s_x4[PTS_AX];      // x as vec4 per point

    const int t = threadIdx.x;
    const int w = t >> 6;              // wave id == head
    const int l = t & 63;
    const int l31 = l & 31, lh = l >> 5;
    const int b  = blockIdx.x / SEGS_AX;
    const int sb = blockIdx.x % SEGS_AX;
    const int pbase = b * NPTS + sb * PTS_AX;

    // stage a transposed (bf16) and x (vec4)
    for (int pt = t; pt < PTS_AX; pt += 256) {
        const float* arow = a + (size_t)(pbase + pt) * CIN;
#pragma unroll
        for (int v = 0; v < 8; ++v) {
            float4 f = ((const float4*)arow)[v];
            s_aT[4*v+0][pt] = f2bf(f.x);
            s_aT[4*v+1][pt] = f2bf(f.y);
            s_aT[4*v+2][pt] = f2bf(f.z);
            s_aT[4*v+3][pt] = f2bf(f.w);
        }
    }
    for (int idx = t; idx < PTS_AX*3; idx += 256) {
        const float v = x[(size_t)pbase * 3 + idx];
        const int pt = idx / 3;
        ((float*)&s_x4[pt])[idx - 3*pt] = v;
    }
    // x_modes row for lane's g = l31
    const float xm0 = x_modes[(w*NM + l31)*3 + 0];
    const float xm1 = x_modes[(w*NM + l31)*3 + 1];
    const float xm2 = x_modes[(w*NM + l31)*3 + 2];

    floatx16 accre = zero16(), accim = zero16();
    __syncthreads();   // only block barrier

    for (int c = 0; c < PTS_AX/32; ++c) {
        const int p0 = c * 32;
        // ---- X frags direct: B-op [n=g=l31][k=pt], pt = p0+kh*16+lh*8+j ----
        short8 xre[2], xim[2];
#pragma unroll
        for (int kh = 0; kh < 2; ++kh) {
            frag8 re_, im_;
#pragma unroll
            for (int j = 0; j < 8; j += 2) {
                const int pl = p0 + kh*16 + lh*8 + j;
                const float4 v0 = s_x4[pl], v1 = s_x4[pl + 1];
                const float q0 = v0.x*xm0 + v0.y*xm1 + v0.z*xm2;
                const float q1 = v1.x*xm0 + v1.y*xm1 + v1.z*xm2;
                re_.u[j>>1] = pk2( __builtin_amdgcn_cosf(q0),  __builtin_amdgcn_cosf(q1));
                im_.u[j>>1] = pk2(-__builtin_amdgcn_sinf(q0), -__builtin_amdgcn_sinf(q1));
            }
            xre[kh] = re_.v; xim[kh] = im_.v;
        }
        // ---- M accumulate: A-op a^T [m=i=l31][k=pt] straight from LDS ----
#pragma unroll
        for (int kh = 0; kh < 2; ++kh) {
            short8 atf = frag_lds(&s_aT[l31][p0 + kh*16 + lh*8]);
            accre = MFMA32(atf, xre[kh], accre, 0, 0, 0);
            accim = MFMA32(atf, xim[kh], accim, 0, 0, 0);
        }
    }

    // M[i,g]: i = row(r), g = l31 (32x32x16 C/D layout)
    if (use_part) {
        float* pr = part + (size_t)blockIdx.x * 8192;
#pragma unroll
        for (int r = 0; r < 16; ++r) {
            const int ir = (r & 3) + 8*(r >> 2) + 4*lh;
            const int idx = (w*NM + ir)*NM + l31;
            pr[idx]        = accre[r];
            pr[idx + 4096] = accim[r];
        }
    } else {
        float* Mre = AX;
        float* Mim = AX + BATCH*NHEADS*NM*NM;
#pragma unroll
        for (int r = 0; r < 16; ++r) {
            const int ir = (r & 3) + 8*(r >> 2) + 4*lh;
            const int idx = b*4096 + (w*NM + ir)*NM + l31;
            atomicAdd(&Mre[idx], accre[r]);
            atomicAdd(&Mim[idx], accim[r]);
        }
    }
}

// ---------------------------------------------------------------------------
// k_red: M = sum of 384 per-block partials, float4-vectorized (1 KB/wave-
// instr, 12 fully-unrolled in-flight loads per thread). 512 blocks; each
// block owns one 32-float slice of M. No fences, no cross-block sync.
// ---------------------------------------------------------------------------
__global__ void k_red(const float* __restrict__ part, float* __restrict__ AX)
{
    __shared__ float4 s_r[32][8];
    const int t = threadIdx.x;
    const int bb = blockIdx.x >> 8;           // batch
    const int idx0 = (blockIdx.x & 255) * 32; // flat idx within [0,8192)
    const int c = t & 7, s = t >> 3;

    const float4* p4 = (const float4*)part;
    const size_t colbase = (size_t)bb * SEGS_AX * 2048 + (idx0 >> 2) + c;
    float4 acc = {0.f, 0.f, 0.f, 0.f};
#pragma unroll
    for (int k = 0; k < 12; ++k) {            // 12*32 = 384 = SEGS_AX
        const float4 v = p4[colbase + (size_t)(s + 32*k) * 2048];
        acc.x += v.x; acc.y += v.y; acc.z += v.z; acc.w += v.w;
    }
    s_r[s][c] = acc;
    __syncthreads();
    if (t < 8) {
        float4 v = s_r[0][t];
#pragma unroll
        for (int ss = 1; ss < 32; ++ss) {
            const float4 u = s_r[ss][t];
            v.x += u.x; v.y += u.y; v.z += u.z; v.w += u.w;
        }
        float* dst = (idx0 < 4096) ? (AX + bb*4096 + idx0)
                                   : (AX + 8192 + bb*4096 + (idx0 - 4096));
        ((float4*)dst)[t] = v;
    }
}

// ---------------------------------------------------------------------------
// k_w: W[b,h,o,g] = INV_N * sum_f um[h,f,o] * sum_i am[h,f,i] * M[b,h,i,g]
// Tiny all-f32 two-stage contraction (T = am.M, W = um.T), bf16 out.
// 8 blocks (one per b,h) x 256 threads. (Round-1 version, proven.)
// ---------------------------------------------------------------------------
__global__ void k_w(const float* __restrict__ AX, const float* __restrict__ a_modes,
                    const float* __restrict__ u_modes, ushort_t* __restrict__ W)
{
    __shared__ float sM[2][NM][NM];      // [re/im][i][g]
    __shared__ float sT[2][NM][NM + 1];  // [re/im][f][g]
    const int t = threadIdx.x;
    const int b = blockIdx.x >> 2, h = blockIdx.x & 3;
    const float* Mre = AX + b*4096 + h*1024;
    const float* Mim = AX + BATCH*4096 + b*4096 + h*1024;
    for (int i = t; i < 1024; i += 256) {
        sM[0][i >> 5][i & 31] = Mre[i];
        sM[1][i >> 5][i & 31] = Mim[i];
    }
    __syncthreads();
    const int fo = t >> 3;               // stage1: f, stage2: o
    const int g0 = (t & 7) * 4;
    {
        const float* am = a_modes + (h*NM + fo)*CIN;
        float tr[4] = {0,0,0,0}, ti[4] = {0,0,0,0};
#pragma unroll 8
        for (int i = 0; i < CIN; ++i) {
            const float wv = am[i];
#pragma unroll
            for (int j = 0; j < 4; ++j) {
                tr[j] += wv * sM[0][i][g0+j];
                ti[j] += wv * sM[1][i][g0+j];
            }
        }
#pragma unroll
        for (int j = 0; j < 4; ++j) { sT[0][fo][g0+j] = tr[j]; sT[1][fo][g0+j] = ti[j]; }
    }
    __syncthreads();
    {
        float wr[4] = {0,0,0,0}, wi[4] = {0,0,0,0};
#pragma unroll 8
        for (int f = 0; f < NM; ++f) {
            const float wv = u_modes[(h*NM + f)*COUT + fo];
#pragma unroll
            for (int j = 0; j < 4; ++j) {
                wr[j] += wv * sT[0][f][g0+j];
                wi[j] += wv * sT[1][f][g0+j];
            }
        }
        ushort_t* Wre = W + (size_t)blockIdx.x * 1024;   // [b][h][o][g]
        ushort_t* Wim = Wre + 8192;
#pragma unroll
        for (int j = 0; j < 4; ++j) {
            Wre[fo*NM + g0 + j] = f2bf(wr[j] * INV_N);
            Wim[fo*NM + g0 + j] = f2bf(wi[j] * INV_N);
        }
    }
}

// ---------------------------------------------------------------------------
// k_out: out = gelu( Re(Y*W) + a.fc_w^T + fc_b ); Y frags built directly.
// Wave = 32 points; one __syncthreads total. (Unchanged.)
// ---------------------------------------------------------------------------
__global__ __launch_bounds__(256, 4) void k_out(
    const float* __restrict__ a, const float* __restrict__ y,
    const float* __restrict__ y_modes, const ushort_t* __restrict__ Wg,
    const float* __restrict__ fc_w, const float* __restrict__ fc_b,
    float* __restrict__ out)
{
    __shared__ ushort_t s_Wre[NHEADS][NM][PAD];  // [h][o][g]
    __shared__ ushort_t s_Wim[NHEADS][NM][PAD];
    __shared__ float4   s_ym4[NHEADS][NM];       // y_modes vec4 per (h,g)
    __shared__ float4   s_y4[128];               // y vec4 per point
    __shared__ ushort_t s_ah[128][PAD];          // a tile bf16 [pt][i]

    const int t = threadIdx.x, w = t >> 6, l = t & 63;
    const int l31 = l & 31, lh = l >> 5;
    const int b  = blockIdx.x / SEGS_OUT;
    const int sb = blockIdx.x % SEGS_OUT;
    const int pblock = b * NPTS + sb * 128;
    const int pwave  = pblock + w * 32;

    // ---- stage ----
    {
        const unsigned* wr = (const unsigned*)Wg + b*2048;
        const unsigned* wi = (const unsigned*)(Wg + 8192) + b*2048;
        for (int idx2 = t; idx2 < 2048; idx2 += 256) {
            const int h = idx2 >> 9, o = (idx2 >> 4) & 31, g2 = (idx2 & 15) * 2;
            *(unsigned*)&s_Wre[h][o][g2] = wr[idx2];
            *(unsigned*)&s_Wim[h][o][g2] = wi[idx2];
        }
    }
    if (t < 128) {
        const int h = t >> 5, g = t & 31;
        const float* p = y_modes + (h*NM + g)*3;
        float4 v; v.x = p[0]; v.y = p[1]; v.z = p[2]; v.w = 0.f;
        s_ym4[h][g] = v;
    }
    for (int idx = t; idx < 128*3; idx += 256) {
        const float v = y[(size_t)pblock * 3 + idx];
        const int pt = idx / 3;
        ((float*)&s_y4[pt])[idx - 3*pt] = v;
    }
    if (t < 128) {
        const float* arow = a + (size_t)(pblock + t) * CIN;
        unsigned* dst = (unsigned*)&s_ah[t][0];
#pragma unroll
        for (int v = 0; v < 8; ++v) {
            float4 f = ((const float4*)arow)[v];
            dst[2*v]   = pk2(f.x, f.y);
            dst[2*v+1] = pk2(f.z, f.w);
        }
    }
    // fc_w hi/lo split frags: B-op [n=o=l31][k=i]
    short8 whi[2], wlo[2];
#pragma unroll
    for (int kh = 0; kh < 2; ++kh) {
        const float* p = fc_w + l31*CIN + kh*16 + lh*8;
        float4 f0 = ((const float4*)p)[0], f1 = ((const float4*)p)[1];
        float v[8] = {f0.x,f0.y,f0.z,f0.w,f1.x,f1.y,f1.z,f1.w};
        frag8 hi, lo;
#pragma unroll
        for (int j = 0; j < 8; ++j) {
            const ushort_t hb = f2bf(v[j]);
            hi.s[j] = hb;
            lo.s[j] = f2bf(v[j] - bf2f(hb));
        }
        whi[kh] = hi.v; wlo[kh] = lo.v;
    }
    const float fb = fc_b[l31];

    __syncthreads();   // only block barrier
    const float4 y3 = s_y4[w*32 + l31];

    // ---- skip: D[pt][o] = sum_i a[pt][i]*(whi+wlo)[o][i] ----
    floatx16 acc = zero16();
#pragma unroll
    for (int kh = 0; kh < 2; ++kh) {
        short8 af = frag_lds(&s_ah[w*32 + l31][kh*16 + lh*8]);  // A-op [m=pt][k=i]
        acc = MFMA32(af, whi[kh], acc, 0, 0, 0);
        acc = MFMA32(af, wlo[kh], acc, 0, 0, 0);
    }
    // ---- heads: acc += Yre.Wre + (-Yim).Wim ----
    for (int h = 0; h < NHEADS; ++h) {
        short8 yre[2], yim[2];
#pragma unroll
        for (int kh = 0; kh < 2; ++kh) {
            frag8 re_, im_;
#pragma unroll
            for (int j = 0; j < 8; j += 2) {
                const int g0 = kh*16 + lh*8 + j;
                const float4 m0 = s_ym4[h][g0], m1 = s_ym4[h][g0 + 1];
                const float p0 = y3.x*m0.x + y3.y*m0.y + y3.z*m0.z;
                const float p1 = y3.x*m1.x + y3.y*m1.y + y3.z*m1.z;
                re_.u[j>>1] = pk2( __builtin_amdgcn_cosf(p0),  __builtin_amdgcn_cosf(p1));
                im_.u[j>>1] = pk2(-__builtin_amdgcn_sinf(p0), -__builtin_amdgcn_sinf(p1));
            }
            yre[kh] = re_.v; yim[kh] = im_.v;
        }
#pragma unroll
        for (int kh = 0; kh < 2; ++kh) {
            short8 wrf = frag_lds(&s_Wre[h][l31][kh*16 + lh*8]);  // B-op [n=o][k=g]
            short8 wif = frag_lds(&s_Wim[h][l31][kh*16 + lh*8]);
            acc = MFMA32(yre[kh], wrf, acc, 0, 0, 0);
            acc = MFMA32(yim[kh], wif, acc, 0, 0, 0);
        }
    }
    // ---- epilogue: bias + exact GELU + store ----
#pragma unroll
    for (int r = 0; r < 16; ++r) {
        const int ptr_ = (r & 3) + 8*(r >> 2) + 4*lh;
        const float z = acc[r] + fb;
        out[(size_t)(pwave + ptr_) * COUT + l31] =
            0.5f * z * (1.0f + erff(z * 0.70710678118654752f));
    }
}

extern "C" void kernel_launch(void* const* d_in, const int* in_sizes, int n_in,
                              void* d_out, int out_size, void* d_ws, size_t ws_size,
                              hipStream_t stream) {
    (void)in_sizes; (void)n_in; (void)out_size;
    const float* a       = (const float*)d_in[0];
    const float* x       = (const float*)d_in[1];
    const float* y       = (const float*)d_in[2];
    const float* a_modes = (const float*)d_in[3];
    const float* x_modes = (const float*)d_in[4];
    const float* y_modes = (const float*)d_in[5];
    const float* u_modes = (const float*)d_in[6];
    const float* fc_w    = (const float*)d_in[7];
    const float* fc_b    = (const float*)d_in[8];
    float* out  = (float*)d_out;
    float*    AX   = (float*)d_ws;                          // 16384 f32 = 64 KB (holds M)
    ushort_t* W    = (ushort_t*)((char*)d_ws + 65536);      // 16384 bf16 = 32 KB
    float*    part = (float*)((char*)d_ws + 98304);         // 768*8192 f32 = 25.2 MB

    const size_t need = 98304 + (size_t)BATCH * SEGS_AX * 8192 * sizeof(float);
    const int use_part = (ws_size >= need) ? 1 : 0;

    if (!use_part) hipMemsetAsync(AX, 0, 65536, stream);  // atomic fallback needs zeroed M
    k_ax<<<BATCH * SEGS_AX, 256, 0, stream>>>(a, x, x_modes, AX, part, use_part);
    if (use_part) k_red<<<NRED, 256, 0, stream>>>(part, AX);
    else          k_w<<<8, 256, 0, stream>>>(AX, a_modes, u_modes, W);
    if (use_part) k_w<<<8, 256, 0, stream>>>(AX, a_modes, u_modes, W);
    k_out<<<BATCH * SEGS_OUT, 256, 0, stream>>>(a, y, y_modes, W, fc_w, fc_b, out);
}

// Round 4
// 147.724 us; speedup vs baseline: 1.1754x; 1.0042x over previous
//
#include <hip/hip_runtime.h>
#include <hip/hip_bf16.h>
#include <math.h>

#define NHEADS 4
#define NM 32
#define CIN 32
#define COUT 32
#define BATCH 2
#define NPTS (48*48*48)           // 110592 per batch
#define PAD 36                    // padded LDS row (bf16) for k_out tiles
#define PTS_AX 432                // points per k_ax block (27 chunks of 16)
#define NCH 27                    // 16-point chunks per block (one K=16 MFMA pair each)
#define SEGS_AX (NPTS/PTS_AX)     // 256 -> grid 512 = exactly 2 blocks/CU
#define PADT 436                  // s_aT row stride (ushort): 872B = 8B-aligned,
                                  // bank step 218%32=26 -> 2-way aliasing (free, m136)
#define SEGS_OUT (NPTS/128)       // 864
#define NRED 512                  // reduction blocks (16384 floats / 32 per block)
#define INV_N (1.0f / (float)NPTS)

typedef unsigned short ushort_t;
typedef __attribute__((ext_vector_type(8))) short short8;     // 8 x bf16 frag
typedef __attribute__((ext_vector_type(16))) float floatx16;  // 32x32 C/D frag

#define MFMA32 __builtin_amdgcn_mfma_f32_32x32x16_bf16

union frag8 { short8 v; uint2 u2[2]; unsigned u[4]; ushort_t s[8]; };

__device__ __forceinline__ floatx16 zero16() {
    floatx16 z;
#pragma unroll
    for (int i = 0; i < 16; ++i) z[i] = 0.0f;
    return z;
}
__device__ __forceinline__ ushort_t f2bf(float f) {
    __hip_bfloat16 h = __float2bfloat16(f);
    return *(ushort_t*)&h;
}
__device__ __forceinline__ float bf2f(ushort_t u) {
    union { unsigned i; float f; } v; v.i = ((unsigned)u) << 16; return v.f;
}
__device__ __forceinline__ unsigned pk2(float a, float b) {
    return (unsigned)f2bf(a) | ((unsigned)f2bf(b) << 16);
}
__device__ __forceinline__ short8 frag_lds(const ushort_t* p) {
    frag8 r;
    r.u2[0] = *(const uint2*)p;
    r.u2[1] = *(const uint2*)(p + 4);
    return r.v;
}

// ---------------------------------------------------------------------------
// k_ax: M[b,h,i,g] = sum_n a[n,i]*X[n,g]. a staged TRANSPOSED in LDS once;
// X built directly into B-op fragments. Wave = head. One __syncthreads.
// Chunk = 16 points = one K=16 MFMA pair -> PTS_AX=432 divides NPTS into
// 512 equal blocks (2/CU exact), shrinking partials 25.2 -> 16.8 MB.
// ---------------------------------------------------------------------------
__global__ __launch_bounds__(256, 4) void k_ax(
    const float* __restrict__ a, const float* __restrict__ x,
    const float* __restrict__ x_modes,
    float* __restrict__ AX, float* __restrict__ part, int use_part)
{
    __shared__ ushort_t s_aT[CIN][PADT];   // a^T bf16 [i][pt]  (32 x 872B = 27.9 KB)
    __shared__ float4   s_x4[PTS_AX];      // x as vec4 per point (6.9 KB)

    const int t = threadIdx.x;
    const int w = t >> 6;              // wave id == head
    const int l = t & 63;
    const int l31 = l & 31, lh = l >> 5;
    const int b  = blockIdx.x / SEGS_AX;
    const int sb = blockIdx.x % SEGS_AX;
    const int pbase = b * NPTS + sb * PTS_AX;

    // stage a transposed (bf16) and x (vec4)
    for (int pt = t; pt < PTS_AX; pt += 256) {
        const float* arow = a + (size_t)(pbase + pt) * CIN;
#pragma unroll
        for (int v = 0; v < 8; ++v) {
            float4 f = ((const float4*)arow)[v];
            s_aT[4*v+0][pt] = f2bf(f.x);
            s_aT[4*v+1][pt] = f2bf(f.y);
            s_aT[4*v+2][pt] = f2bf(f.z);
            s_aT[4*v+3][pt] = f2bf(f.w);
        }
    }
    for (int idx = t; idx < PTS_AX*3; idx += 256) {
        const float v = x[(size_t)pbase * 3 + idx];
        const int pt = idx / 3;
        ((float*)&s_x4[pt])[idx - 3*pt] = v;
    }
    // x_modes row for lane's g = l31
    const float xm0 = x_modes[(w*NM + l31)*3 + 0];
    const float xm1 = x_modes[(w*NM + l31)*3 + 1];
    const float xm2 = x_modes[(w*NM + l31)*3 + 2];

    floatx16 accre = zero16(), accim = zero16();
    __syncthreads();   // only block barrier

    for (int c = 0; c < NCH; ++c) {
        const int p0 = c * 16;
        // ---- X frag direct: B-op [n=g=l31][k=pt], pt = p0+lh*8+j ----
        short8 xre, xim;
        {
            frag8 re_, im_;
#pragma unroll
            for (int j = 0; j < 8; j += 2) {
                const int pl = p0 + lh*8 + j;
                const float4 v0 = s_x4[pl], v1 = s_x4[pl + 1];
                const float q0 = v0.x*xm0 + v0.y*xm1 + v0.z*xm2;
                const float q1 = v1.x*xm0 + v1.y*xm1 + v1.z*xm2;
                re_.u[j>>1] = pk2( __builtin_amdgcn_cosf(q0),  __builtin_amdgcn_cosf(q1));
                im_.u[j>>1] = pk2(-__builtin_amdgcn_sinf(q0), -__builtin_amdgcn_sinf(q1));
            }
            xre = re_.v; xim = im_.v;
        }
        // ---- M accumulate: A-op a^T [m=i=l31][k=pt] straight from LDS ----
        short8 atf = frag_lds(&s_aT[l31][p0 + lh*8]);
        accre = MFMA32(atf, xre, accre, 0, 0, 0);
        accim = MFMA32(atf, xim, accim, 0, 0, 0);
    }

    // M[i,g]: i = row(r), g = l31 (32x32x16 C/D layout)
    if (use_part) {
        float* pr = part + (size_t)blockIdx.x * 8192;
#pragma unroll
        for (int r = 0; r < 16; ++r) {
            const int ir = (r & 3) + 8*(r >> 2) + 4*lh;
            const int idx = (w*NM + ir)*NM + l31;
            pr[idx]        = accre[r];
            pr[idx + 4096] = accim[r];
        }
    } else {
        float* Mre = AX;
        float* Mim = AX + BATCH*NHEADS*NM*NM;
#pragma unroll
        for (int r = 0; r < 16; ++r) {
            const int ir = (r & 3) + 8*(r >> 2) + 4*lh;
            const int idx = b*4096 + (w*NM + ir)*NM + l31;
            atomicAdd(&Mre[idx], accre[r]);
            atomicAdd(&Mim[idx], accim[r]);
        }
    }
}

// ---------------------------------------------------------------------------
// k_red: M = sum of 256 per-batch partials, float4-vectorized (1 KB/wave-
// instr, 8 fully-unrolled in-flight loads per thread). 512 blocks; each
// block owns one 32-float slice of M. No fences, no cross-block sync.
// ---------------------------------------------------------------------------
__global__ void k_red(const float* __restrict__ part, float* __restrict__ AX)
{
    __shared__ float4 s_r[32][8];
    const int t = threadIdx.x;
    const int bb = blockIdx.x >> 8;           // batch
    const int idx0 = (blockIdx.x & 255) * 32; // flat idx within [0,8192)
    const int c = t & 7, s = t >> 3;

    const float4* p4 = (const float4*)part;
    const size_t colbase = (size_t)bb * SEGS_AX * 2048 + (idx0 >> 2) + c;
    float4 acc = {0.f, 0.f, 0.f, 0.f};
#pragma unroll
    for (int k = 0; k < 8; ++k) {             // 8*32 = 256 = SEGS_AX
        const float4 v = p4[colbase + (size_t)(s + 32*k) * 2048];
        acc.x += v.x; acc.y += v.y; acc.z += v.z; acc.w += v.w;
    }
    s_r[s][c] = acc;
    __syncthreads();
    if (t < 8) {
        float4 v = s_r[0][t];
#pragma unroll
        for (int ss = 1; ss < 32; ++ss) {
            const float4 u = s_r[ss][t];
            v.x += u.x; v.y += u.y; v.z += u.z; v.w += u.w;
        }
        float* dst = (idx0 < 4096) ? (AX + bb*4096 + idx0)
                                   : (AX + 8192 + bb*4096 + (idx0 - 4096));
        ((float4*)dst)[t] = v;
    }
}

// ---------------------------------------------------------------------------
// k_w: W[b,h,o,g] = INV_N * sum_f um[h,f,o] * sum_i am[h,f,i] * M[b,h,i,g]
// Tiny all-f32 two-stage contraction (T = am.M, W = um.T), bf16 out.
// 8 blocks (one per b,h) x 256 threads.
// ---------------------------------------------------------------------------
__global__ void k_w(const float* __restrict__ AX, const float* __restrict__ a_modes,
                    const float* __restrict__ u_modes, ushort_t* __restrict__ W)
{
    __shared__ float sM[2][NM][NM];      // [re/im][i][g]
    __shared__ float sT[2][NM][NM + 1];  // [re/im][f][g]
    const int t = threadIdx.x;
    const int b = blockIdx.x >> 2, h = blockIdx.x & 3;
    const float* Mre = AX + b*4096 + h*1024;
    const float* Mim = AX + BATCH*4096 + b*4096 + h*1024;
    for (int i = t; i < 1024; i += 256) {
        sM[0][i >> 5][i & 31] = Mre[i];
        sM[1][i >> 5][i & 31] = Mim[i];
    }
    __syncthreads();
    const int fo = t >> 3;               // stage1: f, stage2: o
    const int g0 = (t & 7) * 4;
    {
        const float* am = a_modes + (h*NM + fo)*CIN;
        float tr[4] = {0,0,0,0}, ti[4] = {0,0,0,0};
#pragma unroll 8
        for (int i = 0; i < CIN; ++i) {
            const float wv = am[i];
#pragma unroll
            for (int j = 0; j < 4; ++j) {
                tr[j] += wv * sM[0][i][g0+j];
                ti[j] += wv * sM[1][i][g0+j];
            }
        }
#pragma unroll
        for (int j = 0; j < 4; ++j) { sT[0][fo][g0+j] = tr[j]; sT[1][fo][g0+j] = ti[j]; }
    }
    __syncthreads();
    {
        float wr[4] = {0,0,0,0}, wi[4] = {0,0,0,0};
#pragma unroll 8
        for (int f = 0; f < NM; ++f) {
            const float wv = u_modes[(h*NM + f)*COUT + fo];
#pragma unroll
            for (int j = 0; j < 4; ++j) {
                wr[j] += wv * sT[0][f][g0+j];
                wi[j] += wv * sT[1][f][g0+j];
            }
        }
        ushort_t* Wre = W + (size_t)blockIdx.x * 1024;   // [b][h][o][g]
        ushort_t* Wim = Wre + 8192;
#pragma unroll
        for (int j = 0; j < 4; ++j) {
            Wre[fo*NM + g0 + j] = f2bf(wr[j] * INV_N);
            Wim[fo*NM + g0 + j] = f2bf(wi[j] * INV_N);
        }
    }
}

// ---------------------------------------------------------------------------
// k_out: out = gelu( Re(Y*W) + a.fc_w^T + fc_b ); Y frags built directly.
// Wave = 32 points; one __syncthreads total. (Unchanged.)
// ---------------------------------------------------------------------------
__global__ __launch_bounds__(256, 4) void k_out(
    const float* __restrict__ a, const float* __restrict__ y,
    const float* __restrict__ y_modes, const ushort_t* __restrict__ Wg,
    const float* __restrict__ fc_w, const float* __restrict__ fc_b,
    float* __restrict__ out)
{
    __shared__ ushort_t s_Wre[NHEADS][NM][PAD];  // [h][o][g]
    __shared__ ushort_t s_Wim[NHEADS][NM][PAD];
    __shared__ float4   s_ym4[NHEADS][NM];       // y_modes vec4 per (h,g)
    __shared__ float4   s_y4[128];               // y vec4 per point
    __shared__ ushort_t s_ah[128][PAD];          // a tile bf16 [pt][i]

    const int t = threadIdx.x, w = t >> 6, l = t & 63;
    const int l31 = l & 31, lh = l >> 5;
    const int b  = blockIdx.x / SEGS_OUT;
    const int sb = blockIdx.x % SEGS_OUT;
    const int pblock = b * NPTS + sb * 128;
    const int pwave  = pblock + w * 32;

    // ---- stage ----
    {
        const unsigned* wr = (const unsigned*)Wg + b*2048;
        const unsigned* wi = (const unsigned*)(Wg + 8192) + b*2048;
        for (int idx2 = t; idx2 < 2048; idx2 += 256) {
            const int h = idx2 >> 9, o = (idx2 >> 4) & 31, g2 = (idx2 & 15) * 2;
            *(unsigned*)&s_Wre[h][o][g2] = wr[idx2];
            *(unsigned*)&s_Wim[h][o][g2] = wi[idx2];
        }
    }
    if (t < 128) {
        const int h = t >> 5, g = t & 31;
        const float* p = y_modes + (h*NM + g)*3;
        float4 v; v.x = p[0]; v.y = p[1]; v.z = p[2]; v.w = 0.f;
        s_ym4[h][g] = v;
    }
    for (int idx = t; idx < 128*3; idx += 256) {
        const float v = y[(size_t)pblock * 3 + idx];
        const int pt = idx / 3;
        ((float*)&s_y4[pt])[idx - 3*pt] = v;
    }
    if (t < 128) {
        const float* arow = a + (size_t)(pblock + t) * CIN;
        unsigned* dst = (unsigned*)&s_ah[t][0];
#pragma unroll
        for (int v = 0; v < 8; ++v) {
            float4 f = ((const float4*)arow)[v];
            dst[2*v]   = pk2(f.x, f.y);
            dst[2*v+1] = pk2(f.z, f.w);
        }
    }
    // fc_w hi/lo split frags: B-op [n=o=l31][k=i]
    short8 whi[2], wlo[2];
#pragma unroll
    for (int kh = 0; kh < 2; ++kh) {
        const float* p = fc_w + l31*CIN + kh*16 + lh*8;
        float4 f0 = ((const float4*)p)[0], f1 = ((const float4*)p)[1];
        float v[8] = {f0.x,f0.y,f0.z,f0.w,f1.x,f1.y,f1.z,f1.w};
        frag8 hi, lo;
#pragma unroll
        for (int j = 0; j < 8; ++j) {
            const ushort_t hb = f2bf(v[j]);
            hi.s[j] = hb;
            lo.s[j] = f2bf(v[j] - bf2f(hb));
        }
        whi[kh] = hi.v; wlo[kh] = lo.v;
    }
    const float fb = fc_b[l31];

    __syncthreads();   // only block barrier
    const float4 y3 = s_y4[w*32 + l31];

    // ---- skip: D[pt][o] = sum_i a[pt][i]*(whi+wlo)[o][i] ----
    floatx16 acc = zero16();
#pragma unroll
    for (int kh = 0; kh < 2; ++kh) {
        short8 af = frag_lds(&s_ah[w*32 + l31][kh*16 + lh*8]);  // A-op [m=pt][k=i]
        acc = MFMA32(af, whi[kh], acc, 0, 0, 0);
        acc = MFMA32(af, wlo[kh], acc, 0, 0, 0);
    }
    // ---- heads: acc += Yre.Wre + (-Yim).Wim ----
    for (int h = 0; h < NHEADS; ++h) {
        short8 yre[2], yim[2];
#pragma unroll
        for (int kh = 0; kh < 2; ++kh) {
            frag8 re_, im_;
#pragma unroll
            for (int j = 0; j < 8; j += 2) {
                const int g0 = kh*16 + lh*8 + j;
                const float4 m0 = s_ym4[h][g0], m1 = s_ym4[h][g0 + 1];
                const float p0 = y3.x*m0.x + y3.y*m0.y + y3.z*m0.z;
                const float p1 = y3.x*m1.x + y3.y*m1.y + y3.z*m1.z;
                re_.u[j>>1] = pk2( __builtin_amdgcn_cosf(p0),  __builtin_amdgcn_cosf(p1));
                im_.u[j>>1] = pk2(-__builtin_amdgcn_sinf(p0), -__builtin_amdgcn_sinf(p1));
            }
            yre[kh] = re_.v; yim[kh] = im_.v;
        }
#pragma unroll
        for (int kh = 0; kh < 2; ++kh) {
            short8 wrf = frag_lds(&s_Wre[h][l31][kh*16 + lh*8]);  // B-op [n=o][k=g]
            short8 wif = frag_lds(&s_Wim[h][l31][kh*16 + lh*8]);
            acc = MFMA32(yre[kh], wrf, acc, 0, 0, 0);
            acc = MFMA32(yim[kh], wif, acc, 0, 0, 0);
        }
    }
    // ---- epilogue: bias + exact GELU + store ----
#pragma unroll
    for (int r = 0; r < 16; ++r) {
        const int ptr_ = (r & 3) + 8*(r >> 2) + 4*lh;
        const float z = acc[r] + fb;
        out[(size_t)(pwave + ptr_) * COUT + l31] =
            0.5f * z * (1.0f + erff(z * 0.70710678118654752f));
    }
}

extern "C" void kernel_launch(void* const* d_in, const int* in_sizes, int n_in,
                              void* d_out, int out_size, void* d_ws, size_t ws_size,
                              hipStream_t stream) {
    (void)in_sizes; (void)n_in; (void)out_size;
    const float* a       = (const float*)d_in[0];
    const float* x       = (const float*)d_in[1];
    const float* y       = (const float*)d_in[2];
    const float* a_modes = (const float*)d_in[3];
    const float* x_modes = (const float*)d_in[4];
    const float* y_modes = (const float*)d_in[5];
    const float* u_modes = (const float*)d_in[6];
    const float* fc_w    = (const float*)d_in[7];
    const float* fc_b    = (const float*)d_in[8];
    float* out  = (float*)d_out;
    float*    AX   = (float*)d_ws;                          // 16384 f32 = 64 KB (holds M)
    ushort_t* W    = (ushort_t*)((char*)d_ws + 65536);      // 16384 bf16 = 32 KB
    float*    part = (float*)((char*)d_ws + 98304);         // 512*8192 f32 = 16.8 MB

    const size_t need = 98304 + (size_t)BATCH * SEGS_AX * 8192 * sizeof(float);
    const int use_part = (ws_size >= need) ? 1 : 0;

    if (!use_part) hipMemsetAsync(AX, 0, 65536, stream);  // atomic fallback needs zeroed M
    k_ax<<<BATCH * SEGS_AX, 256, 0, stream>>>(a, x, x_modes, AX, part, use_part);
    if (use_part) k_red<<<NRED, 256, 0, stream>>>(part, AX);
    k_w<<<8, 256, 0, stream>>>(AX, a_modes, u_modes, W);
    k_out<<<BATCH * SEGS_OUT, 256, 0, stream>>>(a, y, y_modes, W, fc_w, fc_b, out);
}